// Round 9
// baseline (82.675 us; speedup 1.0000x reference)
//
#include <hip/hip_runtime.h>

// PillarLayer: fused copy + per-pillar xyz center-of-mass + BEV canvas scatter.
//
// R9 = R5 (zero + direct scatter + NT streaming) with the 45 ds_swizzle
// shuffle-reduce replaced by a DPP reduction (pure VALU, 0 DS ops).
// Theory: R5's wave moved 2KB but issued 45 DS ops (~270 DS-pipe cycles)
// -> DS-limited at ~4.8 TB/s, matching the measured ~4.9. DPP removes it.
//
// DPP reduce (per 32-lane half): row_shr 1,2,4,8 accumulates each 16-lane
// row's sum into its lane 15/31; row_bcast:15 adds lane15 -> lanes 16-31,
// so lane 31 (63) holds the full 32-lane sum. bound_ctrl=1 makes invalid
// sources contribute 0.
//
// Inputs: d_in[0] pillars f32 (P,32,4); d_in[1] coors int32 (P,4) [b,x,y,z];
//         d_in[2] npoints int32 (P); d_in[3] bs; d_in[4] x_l; d_in[5] y_l.
// Output (concat f32): pillars copy | coors as f32 | npoints as f32 |
//         canvas (bs,3,y_l,x_l) with canvas[b][c][y][x] = center_c or 0.

typedef float vfloat4 __attribute__((ext_vector_type(4)));

template <int CTRL>
__device__ __forceinline__ float dpp_add(float x) {
    const int r = __builtin_amdgcn_update_dpp(
        0, __builtin_bit_cast(int, x), CTRL, 0xf, 0xf, true);
    return x + __builtin_bit_cast(float, r);
}

__global__ __launch_bounds__(256) void canvas_zero(float4* __restrict__ dst, long n4) {
    long i = (long)blockIdx.x * blockDim.x + threadIdx.x;
    const long stride = (long)gridDim.x * blockDim.x;
    const float4 z = make_float4(0.f, 0.f, 0.f, 0.f);
    for (; i < n4; i += stride) dst[i] = z;   // cacheable: L3-resident for scatter
}

__global__ __launch_bounds__(256) void pillar_fused(
    const vfloat4* __restrict__ pillars4,  // P*32 (one float4 per point)
    const int4* __restrict__ coors4,       // P [b,x,y,z]
    const int* __restrict__ npoints,       // P
    const int* __restrict__ xlp,           // scalar x_l
    const int* __restrict__ ylp,           // scalar y_l
    vfloat4* __restrict__ out_pillars4,    // P*32
    float4* __restrict__ out_coors4,       // P
    float* __restrict__ out_np,            // P
    float* __restrict__ canvas,            // bs*3*y_l*x_l
    int P)
{
    const int group = blockIdx.x * (blockDim.x >> 5) + (threadIdx.x >> 5);
    const int lane  = threadIdx.x & 31;    // point index within pillar
    if (group >= P) return;
    const int p = group;

    // Coalesced: 32 lanes x 16B = 512B/pillar; wave64 = 1KB contiguous per
    // instruction. NT keeps the 327 MB stream out of L2/L3 so the zeroed
    // canvas stays cache-resident for the scatter RMW below.
    const vfloat4 v = __builtin_nontemporal_load(&pillars4[(long)p * 32 + lane]);
    __builtin_nontemporal_store(v, &out_pillars4[(long)p * 32 + lane]);

    // DPP reduce over the 32-lane half; interleaved x/y/z for ILP.
    // After these 5 steps, lane 31 of each half holds the 32-lane sum.
    float sx = v.x, sy = v.y, sz = v.z;
    sx = dpp_add<0x111>(sx); sy = dpp_add<0x111>(sy); sz = dpp_add<0x111>(sz); // row_shr:1
    sx = dpp_add<0x112>(sx); sy = dpp_add<0x112>(sy); sz = dpp_add<0x112>(sz); // row_shr:2
    sx = dpp_add<0x114>(sx); sy = dpp_add<0x114>(sy); sz = dpp_add<0x114>(sz); // row_shr:4
    sx = dpp_add<0x118>(sx); sy = dpp_add<0x118>(sy); sz = dpp_add<0x118>(sz); // row_shr:8
    sx = dpp_add<0x142>(sx); sy = dpp_add<0x142>(sy); sz = dpp_add<0x142>(sz); // row_bcast:15

    // Tail: 3 lanes per group split the small writes. Lane 31 has the sums.
    if (lane >= 29) {
        const int4 c   = coors4[p];        // same addr across lanes -> broadcast
        const int npts = npoints[p];
        if (lane == 29) {
            out_np[p] = (float)npts;
        } else if (lane == 30) {
            out_coors4[p] = make_float4((float)c.x, (float)c.y, (float)c.z, (float)c.w);
        } else {
            const float inv = 1.0f / (float)npts;
            const int x_l = *xlp;
            const int y_l = *ylp;
            const long cs   = (long)y_l * (long)x_l;        // plane stride
            const long base = (long)c.x * 3l * cs + (long)c.z * (long)x_l + (long)c.y;
            canvas[base]          = sx * inv;
            canvas[base + cs]     = sy * inv;
            canvas[base + 2 * cs] = sz * inv;
        }
    }
}

extern "C" void kernel_launch(void* const* d_in, const int* in_sizes, int n_in,
                              void* d_out, int out_size, void* d_ws, size_t ws_size,
                              hipStream_t stream) {
    const vfloat4* pillars4 = (const vfloat4*)d_in[0];
    const int4* coors4      = (const int4*)d_in[1];
    const int* npoints      = (const int*)d_in[2];
    const int* xlp = (const int*)d_in[4];
    const int* ylp = (const int*)d_in[5];

    const int n_pillars = in_sizes[0];   // P*128
    const int n_coors   = in_sizes[1];   // P*4
    const int P         = in_sizes[2];   // pillar count

    float* out            = (float*)d_out;
    vfloat4* out_pillars4 = (vfloat4*)out;
    float* out_coors      = out + n_pillars;
    float* out_np         = out_coors + n_coors;
    float* canvas         = out_np + P;
    const long canvas_elems = (long)out_size - n_pillars - n_coors - P;  // bs*3*y_l*x_l

    // K1: zero canvas (cacheable -> L3 resident for the scatter RMW).
    const long n4 = canvas_elems >> 2;   // canvas start is 16B-aligned here
    int zblocks = (int)((n4 + 511) / 512);
    if (zblocks > 2048) zblocks = 2048;
    canvas_zero<<<zblocks, 256, 0, stream>>>((float4*)canvas, n4);

    // K2: fused copy + reduce + scatter. 8 pillars per 256-thread block.
    const int groups_per_block = 256 / 32;
    const int blocks = (P + groups_per_block - 1) / groups_per_block;
    pillar_fused<<<blocks, 256, 0, stream>>>(
        pillars4, coors4, npoints, xlp, ylp,
        out_pillars4, (float4*)out_coors, out_np, canvas, P);
}